// Round 6
// baseline (242.322 us; speedup 1.0000x reference)
//
#include <hip/hip_runtime.h>
#include <math.h>

#define DM 1024
#define NH 16
#define DK 64
#define BB 4
#define TT 2048
#define MTOT (BB*TT)   // 8192

typedef __bf16 bf16x8 __attribute__((ext_vector_type(8)));
typedef short  s16x4  __attribute__((ext_vector_type(4)));
typedef float  f32x4  __attribute__((ext_vector_type(4)));

__device__ __forceinline__ short f2bf_s(float f) {
    __bf16 h = (__bf16)f;
    return __builtin_bit_cast(short, h);
}

__device__ __forceinline__ float exp2_fast(float x) {
    float r;
    asm("v_exp_f32 %0, %1" : "=v"(r) : "v"(x));
    return r;
}

// async global->LDS, 16B per lane; LDS dst wave-uniform base, lane i -> base+16i
__device__ __forceinline__ void async_copy16(unsigned short* lds, const unsigned short* g) {
    __builtin_amdgcn_global_load_lds(
        (const __attribute__((address_space(1))) unsigned int*)g,
        (__attribute__((address_space(3))) unsigned int*)lds, 16, 0, 0);
}

// ---------------------------------------------------------------------------
// merged fp32 -> bf16 converts
// ---------------------------------------------------------------------------
__global__ __launch_bounds__(256)
void cvt_all_kernel(const float* __restrict__ x,
                    const float* __restrict__ wq, const float* __restrict__ wk,
                    const float* __restrict__ wv, const float* __restrict__ wo,
                    unsigned short* __restrict__ xb,
                    unsigned short* __restrict__ wqb, unsigned short* __restrict__ wkb,
                    unsigned short* __restrict__ wvb, unsigned short* __restrict__ wob)
{
    const int XB = (MTOT * DM) / 1024;   // 8192
    int bz = blockIdx.x;
    const float* src; unsigned short* dst; int blk;
    if (bz < XB) { src = x; dst = xb; blk = bz; }
    else {
        int t = bz - XB, which = t >> 10;
        blk = t & 1023;
        if (which == 0)      { src = wq; dst = wqb; }
        else if (which == 1) { src = wk; dst = wkb; }
        else if (which == 2) { src = wv; dst = wvb; }
        else                 { src = wo; dst = wob; }
    }
    int i = blk * 256 + threadIdx.x;
    float4 v = ((const float4*)src)[i];
    ushort4 o;
    o.x = (unsigned short)f2bf_s(v.x); o.y = (unsigned short)f2bf_s(v.y);
    o.z = (unsigned short)f2bf_s(v.z); o.w = (unsigned short)f2bf_s(v.w);
    ((ushort4*)dst)[i] = o;
}

// ---------------------------------------------------------------------------
// bf16 MFMA GEMM, BK=64, XOR-swizzled LDS, global_load_lds staging.
// MODE 0: fp32 row-major out. MODE 1: bf16; z=0 Q(+RoPE+prescale) (B,H,T,DK),
// z=1 K(+RoPE) (B,H,T,DK), z=2 V written TRANSPOSED directly as (B,H,DK,T).
// RoPE epilogue uses 3 sincos + angle-addition rotations per jp.
// ---------------------------------------------------------------------------
template<int MODE>
__global__ __launch_bounds__(256, 3)
void gemm_bf16_kernel(const unsigned short* __restrict__ X,
                      const unsigned short* __restrict__ W0, const float* __restrict__ b0,
                      const unsigned short* __restrict__ W1, const float* __restrict__ b1,
                      const unsigned short* __restrict__ W2, const float* __restrict__ b2,
                      void* __restrict__ Y0, void* __restrict__ Y1, void* __restrict__ Y2)
{
    const unsigned short* W; const float* bias; void* Yv;
    const int z = blockIdx.z;
    if (z == 0)      { W = W0; bias = b0; Yv = Y0; }
    else if (z == 1) { W = W1; bias = b1; Yv = Y1; }
    else             { W = W2; bias = b2; Yv = Y2; }

    __shared__ __align__(16) unsigned short As[128 * 64];  // 16 KB
    __shared__ __align__(16) unsigned short Bs[128 * 64];  // 16 KB

    const int tid  = threadIdx.x;
    const int w    = tid >> 6, lane = tid & 63;
    const int quad = lane >> 4, lq = lane & 15;
    const int bm = blockIdx.x * 128, bn = blockIdx.y * 128;
    const int wm = (w >> 1) * 64,   wn = (w & 1) * 64;

    const int srow = lane >> 3;                 // 0..7 within the 8-row group
    const int sg   = (lane & 7) ^ srow;         // swizzled source granule
    const int soff = sg * 8;                    // shorts

    f32x4 acc[4][4];
    #pragma unroll
    for (int i = 0; i < 4; ++i)
        #pragma unroll
        for (int j = 0; j < 4; ++j)
            acc[i][j] = {0.f, 0.f, 0.f, 0.f};

    for (int k0 = 0; k0 < DM; k0 += 64) {
        #pragma unroll
        for (int c = 0; c < 4; ++c) {
            int r0 = w * 32 + c * 8;
            async_copy16(&As[r0 * 64], &X[(size_t)(bm + r0 + srow) * DM + k0 + soff]);
            async_copy16(&Bs[r0 * 64], &W[(size_t)(bn + r0 + srow) * DM + k0 + soff]);
        }
        __syncthreads();

        #pragma unroll
        for (int ks = 0; ks < 2; ++ks) {
            const int gsw = ((ks << 2) + quad) ^ (lq & 7);  // physical granule
            bf16x8 af[4], bfr[4];
            #pragma unroll
            for (int i = 0; i < 4; ++i)
                af[i] = *(const bf16x8*)&As[(wm + i*16 + lq) * 64 + gsw * 8];
            #pragma unroll
            for (int j = 0; j < 4; ++j)
                bfr[j] = *(const bf16x8*)&Bs[(wn + j*16 + lq) * 64 + gsw * 8];
            #pragma unroll
            for (int i = 0; i < 4; ++i)
                #pragma unroll
                for (int j = 0; j < 4; ++j)
                    acc[i][j] = __builtin_amdgcn_mfma_f32_16x16x32_bf16(af[i], bfr[j], acc[i][j], 0, 0, 0);
        }
        __syncthreads();
    }

    if (MODE == 0) {
        #pragma unroll
        for (int j = 0; j < 4; ++j) {
            int n = bn + wn + j*16 + lq;
            float bv = bias[n];
            #pragma unroll
            for (int i = 0; i < 4; ++i)
                #pragma unroll
                for (int r = 0; r < 4; ++r) {
                    int m = bm + wm + i*16 + quad*4 + r;
                    ((float*)Yv)[(size_t)m * DM + n] = acc[i][j][r] + bv;
                }
        }
    } else if (z == 2) {
        // V -> V^T (B,H,DK,T) directly. Lane's 4 acc values are 4 consecutive
        // t for fixed dk -> one 8B store each.
        #pragma unroll
        for (int j = 0; j < 4; ++j) {
            int n = bn + wn + j*16 + lq;
            float bv = bias[n];
            int h = n >> 6, dk = n & 63;
            #pragma unroll
            for (int i = 0; i < 4; ++i) {
                int m0 = bm + wm + i*16 + quad*4;
                int b = m0 >> 11, t0 = m0 & 2047;
                ushort4 o;
                o.x = (unsigned short)f2bf_s(acc[i][j][0] + bv);
                o.y = (unsigned short)f2bf_s(acc[i][j][1] + bv);
                o.z = (unsigned short)f2bf_s(acc[i][j][2] + bv);
                o.w = (unsigned short)f2bf_s(acc[i][j][3] + bv);
                *(ushort4*)&((unsigned short*)Yv)[((size_t)(b * NH + h) * DK + dk) * TT + t0] = o;
            }
        }
    } else {
        // Q (z=0) / K (z=1): fused RoPE; Q also pre-scaled by 0.125*log2e.
        // Rotation recurrence: base sincos at t0, then rotate by freq (r-step)
        // and 16*freq (i-step). 3 sincos per jp instead of 16.
        const float QSC = (z == 0) ? 0.125f * 1.44269504f : 1.0f;
        const int h = (bn + wn) >> 6;
        const int b = (bm + wm) >> 11;        // 64-row band never crosses a b boundary
        const int tb0 = ((bm + wm) & 2047) + quad * 4;
        #pragma unroll
        for (int jp = 0; jp < 2; ++jp) {
            int dk1 = jp * 16 + lq;                           // 0..31
            float freq = exp2f(-(float)dk1 * 0.4152410118f);  // 10000^(-dk1/32)
            float bv1 = bias[bn + wn + dk1];
            float bv2 = bias[bn + wn + dk1 + 32];
            float s1, c1, s16v, c16v, sb, cb;
            __sincosf(freq, &s1, &c1);
            __sincosf(16.0f * freq, &s16v, &c16v);
            __sincosf((float)tb0 * freq, &sb, &cb);
            #pragma unroll
            for (int i = 0; i < 4; ++i) {
                float cr = cb, sr = sb;
                #pragma unroll
                for (int r = 0; r < 4; ++r) {
                    int t = tb0 + i*16 + r;
                    float v1 = acc[i][jp][r]     + bv1;
                    float v2 = acc[i][jp + 2][r] + bv2;
                    float o1 = (v1 * cr - v2 * sr) * QSC;
                    float o2 = (v1 * sr + v2 * cr) * QSC;
                    size_t base = ((size_t)(b * NH + h) * TT + t) << 6;
                    ((__bf16*)Yv)[base + dk1]      = (__bf16)o1;
                    ((__bf16*)Yv)[base + dk1 + 32] = (__bf16)o2;
                    float cn = cr * c1 - sr * s1;             // rotate by freq
                    sr = cr * s1 + sr * c1;
                    cr = cn;
                }
                float cbn = cb * c16v - sb * s16v;            // rotate by 16*freq
                sb = cb * s16v + sb * c16v;
                cb = cbn;
            }
        }
    }
}

// ---------------------------------------------------------------------------
// MFMA flash attention (causal), S^T form. LDS double-buffered K/V^T staging
// via global_load_lds with XOR swizzle; ONE q-tile per block, grid (64,32)
// = 2048 blocks at 4 blocks/CU (16 waves/CU).
//
// Occupancy history: 4-tile/2-blk = 82 µs, 2-tile/3-blk = 66 µs -> TLP wins
// over per-wave ILP in this latency-bound kernel. 1 tile shrinks per-thread
// state (~110 peak live) to fit the bound-4 budget (128) WITHOUT the spills
// that killed the 2-tile bound-4 attempt (round 1: ~230 MB scratch).
// Register discipline (both confirmed spill traps still apply):
//   - QK runs in two ks-halves: only 16 kf regs live at a time;
//   - PV runs in two kt-halves: only 16 vb regs live at a time.
// Slot->t = 31-s: expensive blocks dispatch first (LPT), cheap ones fill
// the tail round. setprio(1) around MFMA clusters. One barrier per iter;
// prefetch issued right after it.
// ---------------------------------------------------------------------------
__global__ __launch_bounds__(256, 4)
void attn_kernel(const unsigned short* __restrict__ Q, const unsigned short* __restrict__ K,
                 const unsigned short* __restrict__ Vt_g, unsigned short* __restrict__ ctx)
{
    __shared__ __align__(16) unsigned short KV[2][2][64 * 64];  // 32 KB

    const int tid  = threadIdx.x;
    const int w    = tid >> 6, lane = tid & 63;
    const int quad = lane >> 4, lq = lane & 15;
    const int bh = blockIdx.x;
    const int qt = 31 - blockIdx.y;             // LPT: costly tiles first
    const size_t kbase = (size_t)bh * TT * DK;
    const size_t vbase = (size_t)bh * DK * TT;

    // staging geometry (per wave: rows w*16..w*16+15 of each 64x64 tile)
    const int srow = lane >> 3;                 // 0..7
    const int sg   = (lane & 7) ^ srow;         // swizzled source granule
    const unsigned short* Ksrc = &K[kbase + (size_t)(w*16 + srow) * DK + sg*8];
    const unsigned short* Vsrc = &Vt_g[vbase + (size_t)(w*16 + srow) * TT + sg*8];

    auto issue = [&](int kb, int buf) {
        unsigned short* Kd = &KV[buf][0][w*16*64];
        unsigned short* Vd = &KV[buf][1][w*16*64];
        const unsigned short* ks0 = Ksrc + (size_t)kb * 64 * DK;
        const unsigned short* vs0 = Vsrc + (size_t)kb * 64;
        async_copy16(Kd,          ks0);
        async_copy16(Kd + 8*64,   ks0 + 8*DK);
        async_copy16(Vd,          vs0);
        async_copy16(Vd + 8*64,   vs0 + (size_t)8*TT);
    };

    const int qrow = qt*64 + w*16 + lq;
    bf16x8 qf[2];
    qf[0] = *(const bf16x8*)&Q[kbase + (size_t)qrow * DK + quad*8];
    qf[1] = *(const bf16x8*)&Q[kbase + (size_t)qrow * DK + 32 + quad*8];

    f32x4 accO[4];
    float l_i = 0.f;
    #pragma unroll
    for (int dt = 0; dt < 4; ++dt) accO[dt] = {0.f,0.f,0.f,0.f};

    issue(0, 0);
    for (int kb = 0; kb <= qt; ++kb) {
        __syncthreads();                       // drains this wave's async; readers of other buf done
        if (kb < qt) issue(kb + 1, (kb + 1) & 1);

        const unsigned short* Kb_ = &KV[kb & 1][0][0];
        const unsigned short* Vb_ = &KV[kb & 1][1][0];

        // --- phase 1: QK^T in two ks-halves (16 kf regs live) ---
        f32x4 st[4];
        #pragma unroll
        for (int nt = 0; nt < 4; ++nt) st[nt] = {0.f,0.f,0.f,0.f};
        #pragma unroll
        for (int ks = 0; ks < 2; ++ks) {
            bf16x8 kfh[4];
            #pragma unroll
            for (int nt = 0; nt < 4; ++nt)
                kfh[nt] = *(const bf16x8*)&Kb_[(nt*16 + lq) * 64 +
                                (((ks << 2) + quad) ^ (lq & 7)) * 8];
            __builtin_amdgcn_s_setprio(1);
            #pragma unroll
            for (int nt = 0; nt < 4; ++nt)
                st[nt] = __builtin_amdgcn_mfma_f32_16x16x32_bf16(kfh[nt], qf[ks], st[nt], 0, 0, 0);
            __builtin_amdgcn_s_setprio(0);
        }
        if (kb == qt) {
            #pragma unroll
            for (int nt = 0; nt < 4; ++nt)
                #pragma unroll
                for (int r = 0; r < 4; ++r) {
                    int kc = kb*64 + nt*16 + quad*4 + r;
                    if (kc > qrow) st[nt][r] = -1e30f;
                }
        }
        s16x4 p[4];
        #pragma unroll
        for (int nt = 0; nt < 4; ++nt)
            #pragma unroll
            for (int r = 0; r < 4; ++r) {
                float e = exp2_fast(st[nt][r]);
                l_i += e;
                p[nt][r] = f2bf_s(e);
            }

        // --- phase 2: PV in two kt-halves (16 V-frag regs live) ---
        #pragma unroll
        for (int ktp = 0; ktp < 2; ++ktp) {
            s16x4 vbh[2][4];
            #pragma unroll
            for (int k2 = 0; k2 < 2; ++k2) {
                int kt = ktp*2 + k2;
                #pragma unroll
                for (int dt = 0; dt < 4; ++dt)
                    vbh[k2][dt] = *(const s16x4*)&Vb_[(dt*16 + lq) * 64 +
                                    (((kt << 1) + (quad >> 1)) ^ (lq & 7)) * 8 +
                                    (quad & 1) * 4];
            }
            __builtin_amdgcn_s_setprio(1);
            #pragma unroll
            for (int k2 = 0; k2 < 2; ++k2)
                #pragma unroll
                for (int dt = 0; dt < 4; ++dt)
                    accO[dt] = __builtin_amdgcn_mfma_f32_16x16x16bf16_1k(
                        p[ktp*2 + k2], vbh[k2][dt], accO[dt], 0, 0, 0);
            __builtin_amdgcn_s_setprio(0);
        }
    }

    // ---- epilogue ----
    const int b = bh >> 4, h = bh & 15;
    float l = l_i;
    l += __shfl_xor(l, 16, 64);
    l += __shfl_xor(l, 32, 64);
    float linv = 1.0f / l;
    f32x4 il4;
    #pragma unroll
    for (int r = 0; r < 4; ++r) il4[r] = __shfl(linv, quad*4 + r, 64);
    #pragma unroll
    for (int r = 0; r < 4; ++r) {
        int t = qt*64 + w*16 + quad*4 + r;
        size_t ob = ((size_t)b * TT + t) * DM + h * DK;
        #pragma unroll
        for (int dt = 0; dt < 4; ++dt)
            ((__bf16*)ctx)[ob + dt*16 + lq] = (__bf16)(accO[dt][r] * il4[r]);
    }
}

// ---------------------------------------------------------------------------
extern "C" void kernel_launch(void* const* d_in, const int* in_sizes, int n_in,
                              void* d_out, int out_size, void* d_ws, size_t ws_size,
                              hipStream_t stream)
{
    const float* x   = (const float*)d_in[0];
    const float* WQw = (const float*)d_in[1];
    const float* WQb = (const float*)d_in[2];
    const float* WKw = (const float*)d_in[3];
    const float* WKb = (const float*)d_in[4];
    const float* WVw = (const float*)d_in[5];
    const float* WVb = (const float*)d_in[6];
    const float* WOw = (const float*)d_in[7];
    const float* WOb = (const float*)d_in[8];
    float* out = (float*)d_out;

    unsigned short* ws  = (unsigned short*)d_ws;
    unsigned short* xb  = ws;
    unsigned short* wqb = xb  + (size_t)MTOT * DM;
    unsigned short* wkb = wqb + (size_t)DM * DM;
    unsigned short* wvb = wkb + (size_t)DM * DM;
    unsigned short* wob = wvb + (size_t)DM * DM;
    unsigned short* Qb  = wob + (size_t)DM * DM;
    unsigned short* Kb  = Qb  + (size_t)MTOT * DM;
    unsigned short* Vb  = Kb  + (size_t)MTOT * DM;   // used as ctx
    unsigned short* Vtb = Vb  + (size_t)MTOT * DM;   // V^T (B,H,DK,T), written by GEMM z=2
    unsigned short* ctxb = Vb;

    cvt_all_kernel<<<(MTOT*DM)/1024 + 4*(DM*DM)/1024, 256, 0, stream>>>(
        x, WQw, WKw, WVw, WOw, xb, wqb, wkb, wvb, wob);

    gemm_bf16_kernel<1><<<dim3(MTOT/128, DM/128, 3), 256, 0, stream>>>(
        xb, wqb, WQb, wkb, WKb, wvb, WVb, Qb, Kb, Vtb);

    attn_kernel<<<dim3(BB*NH, 32), 256, 0, stream>>>(Qb, Kb, Vtb, ctxb);

    gemm_bf16_kernel<0><<<dim3(MTOT/128, DM/128, 1), 256, 0, stream>>>(
        ctxb, wob, WOb, wob, WOb, wob, WOb, out, out, out);
}

// Round 8
// 240.180 us; speedup vs baseline: 1.0089x; 1.0089x over previous
//
#include <hip/hip_runtime.h>
#include <math.h>

#define DM 1024
#define NH 16
#define DK 64
#define BB 4
#define TT 2048
#define MTOT (BB*TT)   // 8192

typedef __bf16 bf16x8 __attribute__((ext_vector_type(8)));
typedef short  s16x4  __attribute__((ext_vector_type(4)));
typedef float  f32x4  __attribute__((ext_vector_type(4)));

__device__ __forceinline__ short f2bf_s(float f) {
    __bf16 h = (__bf16)f;
    return __builtin_bit_cast(short, h);
}

__device__ __forceinline__ float exp2_fast(float x) {
    float r;
    asm("v_exp_f32 %0, %1" : "=v"(r) : "v"(x));
    return r;
}

// async global->LDS, 16B per lane; LDS dst wave-uniform base, lane i -> base+16i
__device__ __forceinline__ void async_copy16(unsigned short* lds, const unsigned short* g) {
    __builtin_amdgcn_global_load_lds(
        (const __attribute__((address_space(1))) unsigned int*)g,
        (__attribute__((address_space(3))) unsigned int*)lds, 16, 0, 0);
}

// ---------------------------------------------------------------------------
// merged fp32 -> bf16 converts
// ---------------------------------------------------------------------------
__global__ __launch_bounds__(256)
void cvt_all_kernel(const float* __restrict__ x,
                    const float* __restrict__ wq, const float* __restrict__ wk,
                    const float* __restrict__ wv, const float* __restrict__ wo,
                    unsigned short* __restrict__ xb,
                    unsigned short* __restrict__ wqb, unsigned short* __restrict__ wkb,
                    unsigned short* __restrict__ wvb, unsigned short* __restrict__ wob)
{
    const int XB = (MTOT * DM) / 1024;   // 8192
    int bz = blockIdx.x;
    const float* src; unsigned short* dst; int blk;
    if (bz < XB) { src = x; dst = xb; blk = bz; }
    else {
        int t = bz - XB, which = t >> 10;
        blk = t & 1023;
        if (which == 0)      { src = wq; dst = wqb; }
        else if (which == 1) { src = wk; dst = wkb; }
        else if (which == 2) { src = wv; dst = wvb; }
        else                 { src = wo; dst = wob; }
    }
    int i = blk * 256 + threadIdx.x;
    float4 v = ((const float4*)src)[i];
    ushort4 o;
    o.x = (unsigned short)f2bf_s(v.x); o.y = (unsigned short)f2bf_s(v.y);
    o.z = (unsigned short)f2bf_s(v.z); o.w = (unsigned short)f2bf_s(v.w);
    ((ushort4*)dst)[i] = o;
}

// ---------------------------------------------------------------------------
// bf16 MFMA GEMM, BK=64, XOR-swizzled LDS, global_load_lds staging.
// MODE 0: fp32 row-major out. MODE 1: bf16; z=0 Q(+RoPE+prescale) (B,H,T,DK),
// z=1 K(+RoPE) (B,H,T,DK), z=2 V written TRANSPOSED directly as (B,H,DK,T).
//
// Q/K dk-PERMUTED layout: the rotated pair (o1,o2) for logical dk1 is stored
// at slots (2*dk1, 2*dk1+1) as ONE packed 4B store (dense 64B/quarter-wave
// segment) instead of two scattered 2B stores at dk1 and dk1+32. Legal
// because QK^T only sums over dk and attn loads Q and K through identical
// granule paths -> any common dk permutation leaves S unchanged. V is NOT
// permuted (its dk becomes the output axis).
// RoPE epilogue uses 3 sincos + angle-addition rotations per jp.
// ---------------------------------------------------------------------------
template<int MODE>
__global__ __launch_bounds__(256, 3)
void gemm_bf16_kernel(const unsigned short* __restrict__ X,
                      const unsigned short* __restrict__ W0, const float* __restrict__ b0,
                      const unsigned short* __restrict__ W1, const float* __restrict__ b1,
                      const unsigned short* __restrict__ W2, const float* __restrict__ b2,
                      void* __restrict__ Y0, void* __restrict__ Y1, void* __restrict__ Y2)
{
    const unsigned short* W; const float* bias; void* Yv;
    const int z = blockIdx.z;
    if (z == 0)      { W = W0; bias = b0; Yv = Y0; }
    else if (z == 1) { W = W1; bias = b1; Yv = Y1; }
    else             { W = W2; bias = b2; Yv = Y2; }

    __shared__ __align__(16) unsigned short As[128 * 64];  // 16 KB
    __shared__ __align__(16) unsigned short Bs[128 * 64];  // 16 KB

    const int tid  = threadIdx.x;
    const int w    = tid >> 6, lane = tid & 63;
    const int quad = lane >> 4, lq = lane & 15;
    const int bm = blockIdx.x * 128, bn = blockIdx.y * 128;
    const int wm = (w >> 1) * 64,   wn = (w & 1) * 64;

    const int srow = lane >> 3;                 // 0..7 within the 8-row group
    const int sg   = (lane & 7) ^ srow;         // swizzled source granule
    const int soff = sg * 8;                    // shorts

    f32x4 acc[4][4];
    #pragma unroll
    for (int i = 0; i < 4; ++i)
        #pragma unroll
        for (int j = 0; j < 4; ++j)
            acc[i][j] = {0.f, 0.f, 0.f, 0.f};

    for (int k0 = 0; k0 < DM; k0 += 64) {
        #pragma unroll
        for (int c = 0; c < 4; ++c) {
            int r0 = w * 32 + c * 8;
            async_copy16(&As[r0 * 64], &X[(size_t)(bm + r0 + srow) * DM + k0 + soff]);
            async_copy16(&Bs[r0 * 64], &W[(size_t)(bn + r0 + srow) * DM + k0 + soff]);
        }
        __syncthreads();

        #pragma unroll
        for (int ks = 0; ks < 2; ++ks) {
            const int gsw = ((ks << 2) + quad) ^ (lq & 7);  // physical granule
            bf16x8 af[4], bfr[4];
            #pragma unroll
            for (int i = 0; i < 4; ++i)
                af[i] = *(const bf16x8*)&As[(wm + i*16 + lq) * 64 + gsw * 8];
            #pragma unroll
            for (int j = 0; j < 4; ++j)
                bfr[j] = *(const bf16x8*)&Bs[(wn + j*16 + lq) * 64 + gsw * 8];
            #pragma unroll
            for (int i = 0; i < 4; ++i)
                #pragma unroll
                for (int j = 0; j < 4; ++j)
                    acc[i][j] = __builtin_amdgcn_mfma_f32_16x16x32_bf16(af[i], bfr[j], acc[i][j], 0, 0, 0);
        }
        __syncthreads();
    }

    if (MODE == 0) {
        #pragma unroll
        for (int j = 0; j < 4; ++j) {
            int n = bn + wn + j*16 + lq;
            float bv = bias[n];
            #pragma unroll
            for (int i = 0; i < 4; ++i)
                #pragma unroll
                for (int r = 0; r < 4; ++r) {
                    int m = bm + wm + i*16 + quad*4 + r;
                    ((float*)Yv)[(size_t)m * DM + n] = acc[i][j][r] + bv;
                }
        }
    } else if (z == 2) {
        // V -> V^T (B,H,DK,T) directly. Lane's 4 acc values are 4 consecutive
        // t for fixed dk -> one 8B store each.
        #pragma unroll
        for (int j = 0; j < 4; ++j) {
            int n = bn + wn + j*16 + lq;
            float bv = bias[n];
            int h = n >> 6, dk = n & 63;
            #pragma unroll
            for (int i = 0; i < 4; ++i) {
                int m0 = bm + wm + i*16 + quad*4;
                int b = m0 >> 11, t0 = m0 & 2047;
                ushort4 o;
                o.x = (unsigned short)f2bf_s(acc[i][j][0] + bv);
                o.y = (unsigned short)f2bf_s(acc[i][j][1] + bv);
                o.z = (unsigned short)f2bf_s(acc[i][j][2] + bv);
                o.w = (unsigned short)f2bf_s(acc[i][j][3] + bv);
                *(ushort4*)&((unsigned short*)Yv)[((size_t)(b * NH + h) * DK + dk) * TT + t0] = o;
            }
        }
    } else {
        // Q (z=0) / K (z=1): fused RoPE; Q also pre-scaled by 0.125*log2e.
        // Rotation recurrence: base sincos at t0, then rotate by freq (r-step)
        // and 16*freq (i-step). Packed 4B store at permuted slots 2*dk1(+1).
        const float QSC = (z == 0) ? 0.125f * 1.44269504f : 1.0f;
        const int h = (bn + wn) >> 6;
        const int b = (bm + wm) >> 11;        // 64-row band never crosses a b boundary
        const int tb0 = ((bm + wm) & 2047) + quad * 4;
        #pragma unroll
        for (int jp = 0; jp < 2; ++jp) {
            int dk1 = jp * 16 + lq;                           // 0..31
            float freq = exp2f(-(float)dk1 * 0.4152410118f);  // 10000^(-dk1/32)
            float bv1 = bias[bn + wn + dk1];
            float bv2 = bias[bn + wn + dk1 + 32];
            float s1, c1, s16v, c16v, sb, cb;
            __sincosf(freq, &s1, &c1);
            __sincosf(16.0f * freq, &s16v, &c16v);
            __sincosf((float)tb0 * freq, &sb, &cb);
            #pragma unroll
            for (int i = 0; i < 4; ++i) {
                float cr = cb, sr = sb;
                #pragma unroll
                for (int r = 0; r < 4; ++r) {
                    int t = tb0 + i*16 + r;
                    float v1 = acc[i][jp][r]     + bv1;
                    float v2 = acc[i][jp + 2][r] + bv2;
                    float o1 = (v1 * cr - v2 * sr) * QSC;
                    float o2 = (v1 * sr + v2 * cr) * QSC;
                    size_t base = ((size_t)(b * NH + h) * TT + t) << 6;
                    unsigned int pk = (unsigned int)(unsigned short)f2bf_s(o1)
                                    | ((unsigned int)(unsigned short)f2bf_s(o2) << 16);
                    *(unsigned int*)&((unsigned short*)Yv)[base + 2*dk1] = pk;
                    float cn = cr * c1 - sr * s1;             // rotate by freq
                    sr = cr * s1 + sr * c1;
                    cr = cn;
                }
                float cbn = cb * c16v - sb * s16v;            // rotate by 16*freq
                sb = cb * s16v + sb * c16v;
                cb = cbn;
            }
        }
    }
}

// ---------------------------------------------------------------------------
// MFMA flash attention (causal), S^T form. LDS double-buffered K/V^T staging
// via global_load_lds with XOR swizzle; ONE q-tile per block, grid (64,32)
// = 2048 blocks at 4 blocks/CU (16 waves/CU). KNOWN-GOOD (round 6: 62.9 µs,
// VGPR 52, no spill, passed).
//
// Q/K arrive in the dk-permuted layout (see GEMM comment) — transparent here
// since Q-frag and K-frag consume identical slot ranges (ks*32+quad*8+e).
//
// Register discipline (confirmed spill/fail traps):
//   - 2-tile @ bound-4: round 1 spilled ~230 MB; round 7 FAILED correctness.
//     Do NOT widen per-block state at bound 4.
//   - QK in two ks-halves (16 kf regs live); PV in two kt-halves (16 vb regs).
// Slot->t = 31-s: LPT order, HW backfill keeps the machine full.
// setprio(1) around MFMA clusters. One barrier per iter; prefetch right after.
// ---------------------------------------------------------------------------
__global__ __launch_bounds__(256, 4)
void attn_kernel(const unsigned short* __restrict__ Q, const unsigned short* __restrict__ K,
                 const unsigned short* __restrict__ Vt_g, unsigned short* __restrict__ ctx)
{
    __shared__ __align__(16) unsigned short KV[2][2][64 * 64];  // 32 KB

    const int tid  = threadIdx.x;
    const int w    = tid >> 6, lane = tid & 63;
    const int quad = lane >> 4, lq = lane & 15;
    const int bh = blockIdx.x;
    const int qt = 31 - blockIdx.y;             // LPT: costly tiles first
    const size_t kbase = (size_t)bh * TT * DK;
    const size_t vbase = (size_t)bh * DK * TT;

    // staging geometry (per wave: rows w*16..w*16+15 of each 64x64 tile)
    const int srow = lane >> 3;                 // 0..7
    const int sg   = (lane & 7) ^ srow;         // swizzled source granule
    const unsigned short* Ksrc = &K[kbase + (size_t)(w*16 + srow) * DK + sg*8];
    const unsigned short* Vsrc = &Vt_g[vbase + (size_t)(w*16 + srow) * TT + sg*8];

    auto issue = [&](int kb, int buf) {
        unsigned short* Kd = &KV[buf][0][w*16*64];
        unsigned short* Vd = &KV[buf][1][w*16*64];
        const unsigned short* ks0 = Ksrc + (size_t)kb * 64 * DK;
        const unsigned short* vs0 = Vsrc + (size_t)kb * 64;
        async_copy16(Kd,          ks0);
        async_copy16(Kd + 8*64,   ks0 + 8*DK);
        async_copy16(Vd,          vs0);
        async_copy16(Vd + 8*64,   vs0 + (size_t)8*TT);
    };

    const int qrow = qt*64 + w*16 + lq;
    bf16x8 qf[2];
    qf[0] = *(const bf16x8*)&Q[kbase + (size_t)qrow * DK + quad*8];
    qf[1] = *(const bf16x8*)&Q[kbase + (size_t)qrow * DK + 32 + quad*8];

    f32x4 accO[4];
    float l_i = 0.f;
    #pragma unroll
    for (int dt = 0; dt < 4; ++dt) accO[dt] = {0.f,0.f,0.f,0.f};

    issue(0, 0);
    for (int kb = 0; kb <= qt; ++kb) {
        __syncthreads();                       // drains this wave's async; readers of other buf done
        if (kb < qt) issue(kb + 1, (kb + 1) & 1);

        const unsigned short* Kb_ = &KV[kb & 1][0][0];
        const unsigned short* Vb_ = &KV[kb & 1][1][0];

        // --- phase 1: QK^T in two ks-halves (16 kf regs live) ---
        f32x4 st[4];
        #pragma unroll
        for (int nt = 0; nt < 4; ++nt) st[nt] = {0.f,0.f,0.f,0.f};
        #pragma unroll
        for (int ks = 0; ks < 2; ++ks) {
            bf16x8 kfh[4];
            #pragma unroll
            for (int nt = 0; nt < 4; ++nt)
                kfh[nt] = *(const bf16x8*)&Kb_[(nt*16 + lq) * 64 +
                                (((ks << 2) + quad) ^ (lq & 7)) * 8];
            __builtin_amdgcn_s_setprio(1);
            #pragma unroll
            for (int nt = 0; nt < 4; ++nt)
                st[nt] = __builtin_amdgcn_mfma_f32_16x16x32_bf16(kfh[nt], qf[ks], st[nt], 0, 0, 0);
            __builtin_amdgcn_s_setprio(0);
        }
        if (kb == qt) {
            #pragma unroll
            for (int nt = 0; nt < 4; ++nt)
                #pragma unroll
                for (int r = 0; r < 4; ++r) {
                    int kc = kb*64 + nt*16 + quad*4 + r;
                    if (kc > qrow) st[nt][r] = -1e30f;
                }
        }
        s16x4 p[4];
        #pragma unroll
        for (int nt = 0; nt < 4; ++nt)
            #pragma unroll
            for (int r = 0; r < 4; ++r) {
                float e = exp2_fast(st[nt][r]);
                l_i += e;
                p[nt][r] = f2bf_s(e);
            }

        // --- phase 2: PV in two kt-halves (16 V-frag regs live) ---
        #pragma unroll
        for (int ktp = 0; ktp < 2; ++ktp) {
            s16x4 vbh[2][4];
            #pragma unroll
            for (int k2 = 0; k2 < 2; ++k2) {
                int kt = ktp*2 + k2;
                #pragma unroll
                for (int dt = 0; dt < 4; ++dt)
                    vbh[k2][dt] = *(const s16x4*)&Vb_[(dt*16 + lq) * 64 +
                                    (((kt << 1) + (quad >> 1)) ^ (lq & 7)) * 8 +
                                    (quad & 1) * 4];
            }
            __builtin_amdgcn_s_setprio(1);
            #pragma unroll
            for (int k2 = 0; k2 < 2; ++k2)
                #pragma unroll
                for (int dt = 0; dt < 4; ++dt)
                    accO[dt] = __builtin_amdgcn_mfma_f32_16x16x16bf16_1k(
                        p[ktp*2 + k2], vbh[k2][dt], accO[dt], 0, 0, 0);
            __builtin_amdgcn_s_setprio(0);
        }
    }

    // ---- epilogue ----
    const int b = bh >> 4, h = bh & 15;
    float l = l_i;
    l += __shfl_xor(l, 16, 64);
    l += __shfl_xor(l, 32, 64);
    float linv = 1.0f / l;
    f32x4 il4;
    #pragma unroll
    for (int r = 0; r < 4; ++r) il4[r] = __shfl(linv, quad*4 + r, 64);
    #pragma unroll
    for (int r = 0; r < 4; ++r) {
        int t = qt*64 + w*16 + quad*4 + r;
        size_t ob = ((size_t)b * TT + t) * DM + h * DK;
        #pragma unroll
        for (int dt = 0; dt < 4; ++dt)
            ((__bf16*)ctx)[ob + dt*16 + lq] = (__bf16)(accO[dt][r] * il4[r]);
    }
}

// ---------------------------------------------------------------------------
extern "C" void kernel_launch(void* const* d_in, const int* in_sizes, int n_in,
                              void* d_out, int out_size, void* d_ws, size_t ws_size,
                              hipStream_t stream)
{
    const float* x   = (const float*)d_in[0];
    const float* WQw = (const float*)d_in[1];
    const float* WQb = (const float*)d_in[2];
    const float* WKw = (const float*)d_in[3];
    const float* WKb = (const float*)d_in[4];
    const float* WVw = (const float*)d_in[5];
    const float* WVb = (const float*)d_in[6];
    const float* WOw = (const float*)d_in[7];
    const float* WOb = (const float*)d_in[8];
    float* out = (float*)d_out;

    unsigned short* ws  = (unsigned short*)d_ws;
    unsigned short* xb  = ws;
    unsigned short* wqb = xb  + (size_t)MTOT * DM;
    unsigned short* wkb = wqb + (size_t)DM * DM;
    unsigned short* wvb = wkb + (size_t)DM * DM;
    unsigned short* wob = wvb + (size_t)DM * DM;
    unsigned short* Qb  = wob + (size_t)DM * DM;
    unsigned short* Kb  = Qb  + (size_t)MTOT * DM;
    unsigned short* Vb  = Kb  + (size_t)MTOT * DM;   // used as ctx
    unsigned short* Vtb = Vb  + (size_t)MTOT * DM;   // V^T (B,H,DK,T), written by GEMM z=2
    unsigned short* ctxb = Vb;

    cvt_all_kernel<<<(MTOT*DM)/1024 + 4*(DM*DM)/1024, 256, 0, stream>>>(
        x, WQw, WKw, WVw, WOw, xb, wqb, wkb, wvb, wob);

    gemm_bf16_kernel<1><<<dim3(MTOT/128, DM/128, 3), 256, 0, stream>>>(
        xb, wqb, WQb, wkb, WKb, wvb, WVb, Qb, Kb, Vtb);

    attn_kernel<<<dim3(BB*NH, 32), 256, 0, stream>>>(Qb, Kb, Vtb, ctxb);

    gemm_bf16_kernel<0><<<dim3(MTOT/128, DM/128, 1), 256, 0, stream>>>(
        ctxb, wob, WOb, wob, WOb, wob, WOb, out, out, out);
}

// Round 9
// 225.158 us; speedup vs baseline: 1.0762x; 1.0667x over previous
//
#include <hip/hip_runtime.h>
#include <math.h>

#define DM 1024
#define NH 16
#define DK 64
#define BB 4
#define TT 2048
#define MTOT (BB*TT)   // 8192

typedef __bf16 bf16x8 __attribute__((ext_vector_type(8)));
typedef short  s16x4  __attribute__((ext_vector_type(4)));
typedef short  s16x8  __attribute__((ext_vector_type(8)));
typedef float  f32x4  __attribute__((ext_vector_type(4)));

__device__ __forceinline__ short f2bf_s(float f) {
    __bf16 h = (__bf16)f;
    return __builtin_bit_cast(short, h);
}

__device__ __forceinline__ float exp2_fast(float x) {
    float r;
    asm("v_exp_f32 %0, %1" : "=v"(r) : "v"(x));
    return r;
}

// async global->LDS, 16B per lane; LDS dst wave-uniform base, lane i -> base+16i
__device__ __forceinline__ void async_copy16(unsigned short* lds, const unsigned short* g) {
    __builtin_amdgcn_global_load_lds(
        (const __attribute__((address_space(1))) unsigned int*)g,
        (__attribute__((address_space(3))) unsigned int*)lds, 16, 0, 0);
}

// ---------------------------------------------------------------------------
// merged fp32 -> bf16 converts
// ---------------------------------------------------------------------------
__global__ __launch_bounds__(256)
void cvt_all_kernel(const float* __restrict__ x,
                    const float* __restrict__ wq, const float* __restrict__ wk,
                    const float* __restrict__ wv, const float* __restrict__ wo,
                    unsigned short* __restrict__ xb,
                    unsigned short* __restrict__ wqb, unsigned short* __restrict__ wkb,
                    unsigned short* __restrict__ wvb, unsigned short* __restrict__ wob)
{
    const int XB = (MTOT * DM) / 1024;   // 8192
    int bz = blockIdx.x;
    const float* src; unsigned short* dst; int blk;
    if (bz < XB) { src = x; dst = xb; blk = bz; }
    else {
        int t = bz - XB, which = t >> 10;
        blk = t & 1023;
        if (which == 0)      { src = wq; dst = wqb; }
        else if (which == 1) { src = wk; dst = wkb; }
        else if (which == 2) { src = wv; dst = wvb; }
        else                 { src = wo; dst = wob; }
    }
    int i = blk * 256 + threadIdx.x;
    float4 v = ((const float4*)src)[i];
    ushort4 o;
    o.x = (unsigned short)f2bf_s(v.x); o.y = (unsigned short)f2bf_s(v.y);
    o.z = (unsigned short)f2bf_s(v.z); o.w = (unsigned short)f2bf_s(v.w);
    ((ushort4*)dst)[i] = o;
}

// ---------------------------------------------------------------------------
// bf16 MFMA GEMM, BK=64, XOR-swizzled LDS, global_load_lds staging.
// MODE 0: fp32 row-major out. MODE 1: bf16; z=0 Q(+RoPE+prescale) (B,H,T,DK),
// z=1 K(+RoPE) (B,H,T,DK), z=2 V written TRANSPOSED as (B,H,DK,T) with the
// t-axis PERMUTED inside each 64-block: u=(a,q,r) (a=u>>4, q=(u>>2)&3, r=u&3)
// stored at s=(a>>1)*32+q*8+(a&1)*4+r. This makes one 16B LDS granule hold
// both kt and kt+1 B-fragments for a lane in attn's PV step (b128 reads).
//
// Q/K dk-PERMUTED layout: rotated pair (o1,o2) for logical dk1 stored at
// slots (2*dk1, 2*dk1+1) as ONE packed 4B store. Legal: QK^T only sums over
// dk; attn loads Q and K through identical granule paths.
// RoPE epilogue uses 3 sincos + angle-addition rotations per jp.
// ---------------------------------------------------------------------------
template<int MODE>
__global__ __launch_bounds__(256, 3)
void gemm_bf16_kernel(const unsigned short* __restrict__ X,
                      const unsigned short* __restrict__ W0, const float* __restrict__ b0,
                      const unsigned short* __restrict__ W1, const float* __restrict__ b1,
                      const unsigned short* __restrict__ W2, const float* __restrict__ b2,
                      void* __restrict__ Y0, void* __restrict__ Y1, void* __restrict__ Y2)
{
    const unsigned short* W; const float* bias; void* Yv;
    const int z = blockIdx.z;
    if (z == 0)      { W = W0; bias = b0; Yv = Y0; }
    else if (z == 1) { W = W1; bias = b1; Yv = Y1; }
    else             { W = W2; bias = b2; Yv = Y2; }

    __shared__ __align__(16) unsigned short As[128 * 64];  // 16 KB
    __shared__ __align__(16) unsigned short Bs[128 * 64];  // 16 KB

    const int tid  = threadIdx.x;
    const int w    = tid >> 6, lane = tid & 63;
    const int quad = lane >> 4, lq = lane & 15;
    const int bm = blockIdx.x * 128, bn = blockIdx.y * 128;
    const int wm = (w >> 1) * 64,   wn = (w & 1) * 64;

    const int srow = lane >> 3;                 // 0..7 within the 8-row group
    const int sg   = (lane & 7) ^ srow;         // swizzled source granule
    const int soff = sg * 8;                    // shorts

    f32x4 acc[4][4];
    #pragma unroll
    for (int i = 0; i < 4; ++i)
        #pragma unroll
        for (int j = 0; j < 4; ++j)
            acc[i][j] = {0.f, 0.f, 0.f, 0.f};

    for (int k0 = 0; k0 < DM; k0 += 64) {
        #pragma unroll
        for (int c = 0; c < 4; ++c) {
            int r0 = w * 32 + c * 8;
            async_copy16(&As[r0 * 64], &X[(size_t)(bm + r0 + srow) * DM + k0 + soff]);
            async_copy16(&Bs[r0 * 64], &W[(size_t)(bn + r0 + srow) * DM + k0 + soff]);
        }
        __syncthreads();

        #pragma unroll
        for (int ks = 0; ks < 2; ++ks) {
            const int gsw = ((ks << 2) + quad) ^ (lq & 7);  // physical granule
            bf16x8 af[4], bfr[4];
            #pragma unroll
            for (int i = 0; i < 4; ++i)
                af[i] = *(const bf16x8*)&As[(wm + i*16 + lq) * 64 + gsw * 8];
            #pragma unroll
            for (int j = 0; j < 4; ++j)
                bfr[j] = *(const bf16x8*)&Bs[(wn + j*16 + lq) * 64 + gsw * 8];
            #pragma unroll
            for (int i = 0; i < 4; ++i)
                #pragma unroll
                for (int j = 0; j < 4; ++j)
                    acc[i][j] = __builtin_amdgcn_mfma_f32_16x16x32_bf16(af[i], bfr[j], acc[i][j], 0, 0, 0);
        }
        __syncthreads();
    }

    if (MODE == 0) {
        #pragma unroll
        for (int j = 0; j < 4; ++j) {
            int n = bn + wn + j*16 + lq;
            float bv = bias[n];
            #pragma unroll
            for (int i = 0; i < 4; ++i)
                #pragma unroll
                for (int r = 0; r < 4; ++r) {
                    int m = bm + wm + i*16 + quad*4 + r;
                    ((float*)Yv)[(size_t)m * DM + n] = acc[i][j][r] + bv;
                }
        }
    } else if (z == 2) {
        // V -> V^T (B,H,DK,T), t permuted within each 64-block (see header).
        // Lane's 4 acc values are 4 consecutive t (r=0..3) -> still one 8B
        // store; only the block-internal base address is bit-permuted.
        #pragma unroll
        for (int j = 0; j < 4; ++j) {
            int n = bn + wn + j*16 + lq;
            float bv = bias[n];
            int h = n >> 6, dk = n & 63;
            #pragma unroll
            for (int i = 0; i < 4; ++i) {
                int m0 = bm + wm + i*16 + quad*4;
                int b = m0 >> 11, t0 = m0 & 2047;
                int u0 = t0 & 63;
                int t0n = (t0 & ~63) | (((u0 >> 5) & 1) << 5)
                        | (((u0 >> 2) & 3) << 3) | (((u0 >> 4) & 1) << 2);
                ushort4 o;
                o.x = (unsigned short)f2bf_s(acc[i][j][0] + bv);
                o.y = (unsigned short)f2bf_s(acc[i][j][1] + bv);
                o.z = (unsigned short)f2bf_s(acc[i][j][2] + bv);
                o.w = (unsigned short)f2bf_s(acc[i][j][3] + bv);
                *(ushort4*)&((unsigned short*)Yv)[((size_t)(b * NH + h) * DK + dk) * TT + t0n] = o;
            }
        }
    } else {
        // Q (z=0) / K (z=1): fused RoPE; Q also pre-scaled by 0.125*log2e.
        // Rotation recurrence: base sincos at t0, then rotate by freq (r-step)
        // and 16*freq (i-step). Packed 4B store at permuted slots 2*dk1(+1).
        const float QSC = (z == 0) ? 0.125f * 1.44269504f : 1.0f;
        const int h = (bn + wn) >> 6;
        const int b = (bm + wm) >> 11;        // 64-row band never crosses a b boundary
        const int tb0 = ((bm + wm) & 2047) + quad * 4;
        #pragma unroll
        for (int jp = 0; jp < 2; ++jp) {
            int dk1 = jp * 16 + lq;                           // 0..31
            float freq = exp2f(-(float)dk1 * 0.4152410118f);  // 10000^(-dk1/32)
            float bv1 = bias[bn + wn + dk1];
            float bv2 = bias[bn + wn + dk1 + 32];
            float s1, c1, s16v, c16v, sb, cb;
            __sincosf(freq, &s1, &c1);
            __sincosf(16.0f * freq, &s16v, &c16v);
            __sincosf((float)tb0 * freq, &sb, &cb);
            #pragma unroll
            for (int i = 0; i < 4; ++i) {
                float cr = cb, sr = sb;
                #pragma unroll
                for (int r = 0; r < 4; ++r) {
                    int t = tb0 + i*16 + r;
                    float v1 = acc[i][jp][r]     + bv1;
                    float v2 = acc[i][jp + 2][r] + bv2;
                    float o1 = (v1 * cr - v2 * sr) * QSC;
                    float o2 = (v1 * sr + v2 * cr) * QSC;
                    size_t base = ((size_t)(b * NH + h) * TT + t) << 6;
                    unsigned int pk = (unsigned int)(unsigned short)f2bf_s(o1)
                                    | ((unsigned int)(unsigned short)f2bf_s(o2) << 16);
                    *(unsigned int*)&((unsigned short*)Yv)[base + 2*dk1] = pk;
                    float cn = cr * c1 - sr * s1;             // rotate by freq
                    sr = cr * s1 + sr * c1;
                    cr = cn;
                }
                float cbn = cb * c16v - sb * s16v;            // rotate by 16*freq
                sb = cb * s16v + sb * c16v;
                cb = cbn;
            }
        }
    }
}

// ---------------------------------------------------------------------------
// MFMA flash attention (causal), S^T form. LDS double-buffered K/V^T staging
// via global_load_lds with XOR swizzle; ONE q-tile per block, grid (64,32)
// = 2048 blocks at 4 blocks/CU (16 waves/CU).
//
// This round's deltas vs known-good round-6 structure:
//  - V^T arrives kt-pair-interleaved (see GEMM header): PV reads 8x b128
//    instead of 16x b64 (same bytes, half the LDS read instructions; each
//    b128 = B-frags of kt AND kt+1 via register slices).
//  - softmax denominator via ones-MFMA: accL = mfma(p, ones) accumulates
//    l(q=quad*4+r) directly in accL[r] (B=ones is layout-independent).
//    Removes 16 dependent v_add/iter from the 47%-busy VALU pipe and all
//    epilogue shuffles; adds 4 MFMA/iter on the 34%-busy matrix pipe.
//
// Register discipline (confirmed traps): never widen per-block state at
// bound-4 (round 1 spill, round 7 fail). QK in two ks-halves; PV in two
// P-halves (16 V-frag regs live). Spill tripwire: WRITE_SIZE == 16384 KB.
// Slot->t = 31-s (LPT). setprio(1) around MFMA clusters. One barrier/iter.
// ---------------------------------------------------------------------------
__global__ __launch_bounds__(256, 4)
void attn_kernel(const unsigned short* __restrict__ Q, const unsigned short* __restrict__ K,
                 const unsigned short* __restrict__ Vt_g, unsigned short* __restrict__ ctx)
{
    __shared__ __align__(16) unsigned short KV[2][2][64 * 64];  // 32 KB

    const int tid  = threadIdx.x;
    const int w    = tid >> 6, lane = tid & 63;
    const int quad = lane >> 4, lq = lane & 15;
    const int bh = blockIdx.x;
    const int qt = 31 - blockIdx.y;             // LPT: costly tiles first
    const size_t kbase = (size_t)bh * TT * DK;
    const size_t vbase = (size_t)bh * DK * TT;

    // staging geometry (per wave: rows w*16..w*16+15 of each 64x64 tile)
    const int srow = lane >> 3;                 // 0..7
    const int sg   = (lane & 7) ^ srow;         // swizzled source granule
    const unsigned short* Ksrc = &K[kbase + (size_t)(w*16 + srow) * DK + sg*8];
    const unsigned short* Vsrc = &Vt_g[vbase + (size_t)(w*16 + srow) * TT + sg*8];

    auto issue = [&](int kb, int buf) {
        unsigned short* Kd = &KV[buf][0][w*16*64];
        unsigned short* Vd = &KV[buf][1][w*16*64];
        const unsigned short* ks0 = Ksrc + (size_t)kb * 64 * DK;
        const unsigned short* vs0 = Vsrc + (size_t)kb * 64;
        async_copy16(Kd,          ks0);
        async_copy16(Kd + 8*64,   ks0 + 8*DK);
        async_copy16(Vd,          vs0);
        async_copy16(Vd + 8*64,   vs0 + (size_t)8*TT);
    };

    const int qrow = qt*64 + w*16 + lq;
    bf16x8 qf[2];
    qf[0] = *(const bf16x8*)&Q[kbase + (size_t)qrow * DK + quad*8];
    qf[1] = *(const bf16x8*)&Q[kbase + (size_t)qrow * DK + 32 + quad*8];

    const s16x4 ones = {(short)0x3F80, (short)0x3F80, (short)0x3F80, (short)0x3F80};
    f32x4 accO[4];
    f32x4 accL = {0.f, 0.f, 0.f, 0.f};
    #pragma unroll
    for (int dt = 0; dt < 4; ++dt) accO[dt] = {0.f,0.f,0.f,0.f};

    issue(0, 0);
    for (int kb = 0; kb <= qt; ++kb) {
        __syncthreads();                       // drains this wave's async; readers of other buf done
        if (kb < qt) issue(kb + 1, (kb + 1) & 1);

        const unsigned short* Kb_ = &KV[kb & 1][0][0];
        const unsigned short* Vb_ = &KV[kb & 1][1][0];

        // --- phase 1: QK^T in two ks-halves (16 kf regs live) ---
        f32x4 st[4];
        #pragma unroll
        for (int nt = 0; nt < 4; ++nt) st[nt] = {0.f,0.f,0.f,0.f};
        #pragma unroll
        for (int ks = 0; ks < 2; ++ks) {
            bf16x8 kfh[4];
            #pragma unroll
            for (int nt = 0; nt < 4; ++nt)
                kfh[nt] = *(const bf16x8*)&Kb_[(nt*16 + lq) * 64 +
                                (((ks << 2) + quad) ^ (lq & 7)) * 8];
            __builtin_amdgcn_s_setprio(1);
            #pragma unroll
            for (int nt = 0; nt < 4; ++nt)
                st[nt] = __builtin_amdgcn_mfma_f32_16x16x32_bf16(kfh[nt], qf[ks], st[nt], 0, 0, 0);
            __builtin_amdgcn_s_setprio(0);
        }
        if (kb == qt) {
            #pragma unroll
            for (int nt = 0; nt < 4; ++nt)
                #pragma unroll
                for (int r = 0; r < 4; ++r) {
                    int kc = kb*64 + nt*16 + quad*4 + r;
                    if (kc > qrow) st[nt][r] = -1e30f;
                }
        }
        s16x4 p[4];
        #pragma unroll
        for (int nt = 0; nt < 4; ++nt)
            #pragma unroll
            for (int r = 0; r < 4; ++r)
                p[nt][r] = f2bf_s(exp2_fast(st[nt][r]));

        // --- phase 2: PV in two P-halves; b128 V reads, l via ones-MFMA ---
        #pragma unroll
        for (int P = 0; P < 2; ++P) {
            s16x8 vf[4];
            #pragma unroll
            for (int dt = 0; dt < 4; ++dt)
                vf[dt] = *(const s16x8*)&Vb_[(dt*16 + lq) * 64 +
                                (((P << 2) + quad) ^ (lq & 7)) * 8];
            __builtin_amdgcn_s_setprio(1);
            #pragma unroll
            for (int k2 = 0; k2 < 2; ++k2) {
                const int kt = P*2 + k2;
                accL = __builtin_amdgcn_mfma_f32_16x16x16bf16_1k(p[kt], ones, accL, 0, 0, 0);
                #pragma unroll
                for (int dt = 0; dt < 4; ++dt) {
                    s16x4 vs;
                    if (k2) vs = __builtin_shufflevector(vf[dt], vf[dt], 4, 5, 6, 7);
                    else    vs = __builtin_shufflevector(vf[dt], vf[dt], 0, 1, 2, 3);
                    accO[dt] = __builtin_amdgcn_mfma_f32_16x16x16bf16_1k(
                        p[kt], vs, accO[dt], 0, 0, 0);
                }
            }
            __builtin_amdgcn_s_setprio(0);
        }
    }

    // ---- epilogue: accL[r] = l(q=quad*4+r), identical across lq ----
    const int b = bh >> 4, h = bh & 15;
    f32x4 il4;
    #pragma unroll
    for (int r = 0; r < 4; ++r) il4[r] = 1.0f / accL[r];
    #pragma unroll
    for (int r = 0; r < 4; ++r) {
        int t = qt*64 + w*16 + quad*4 + r;
        size_t ob = ((size_t)b * TT + t) * DM + h * DK;
        #pragma unroll
        for (int dt = 0; dt < 4; ++dt)
            ((__bf16*)ctx)[ob + dt*16 + lq] = (__bf16)(accO[dt][r] * il4[r]);
    }
}

// ---------------------------------------------------------------------------
extern "C" void kernel_launch(void* const* d_in, const int* in_sizes, int n_in,
                              void* d_out, int out_size, void* d_ws, size_t ws_size,
                              hipStream_t stream)
{
    const float* x   = (const float*)d_in[0];
    const float* WQw = (const float*)d_in[1];
    const float* WQb = (const float*)d_in[2];
    const float* WKw = (const float*)d_in[3];
    const float* WKb = (const float*)d_in[4];
    const float* WVw = (const float*)d_in[5];
    const float* WVb = (const float*)d_in[6];
    const float* WOw = (const float*)d_in[7];
    const float* WOb = (const float*)d_in[8];
    float* out = (float*)d_out;

    unsigned short* ws  = (unsigned short*)d_ws;
    unsigned short* xb  = ws;
    unsigned short* wqb = xb  + (size_t)MTOT * DM;
    unsigned short* wkb = wqb + (size_t)DM * DM;
    unsigned short* wvb = wkb + (size_t)DM * DM;
    unsigned short* wob = wvb + (size_t)DM * DM;
    unsigned short* Qb  = wob + (size_t)DM * DM;
    unsigned short* Kb  = Qb  + (size_t)MTOT * DM;
    unsigned short* Vb  = Kb  + (size_t)MTOT * DM;   // used as ctx
    unsigned short* Vtb = Vb  + (size_t)MTOT * DM;   // V^T (B,H,DK,T) permuted, from GEMM z=2
    unsigned short* ctxb = Vb;

    cvt_all_kernel<<<(MTOT*DM)/1024 + 4*(DM*DM)/1024, 256, 0, stream>>>(
        x, WQw, WKw, WVw, WOw, xb, wqb, wkb, wvb, wob);

    gemm_bf16_kernel<1><<<dim3(MTOT/128, DM/128, 3), 256, 0, stream>>>(
        xb, wqb, WQb, wkb, WKb, wvb, WVb, Qb, Kb, Vtb);

    attn_kernel<<<dim3(BB*NH, 32), 256, 0, stream>>>(Qb, Kb, Vtb, ctxb);

    gemm_bf16_kernel<0><<<dim3(MTOT/128, DM/128, 1), 256, 0, stream>>>(
        ctxb, wob, WOb, wob, WOb, wob, WOb, out, out, out);
}